// Round 4
// baseline (146.440 us; speedup 1.0000x reference)
//
#include <hip/hip_runtime.h>

#define NIN 784
#define WIDTH 1024
#define HALF 512
#define DEPTH 8
#define BDEPTH 10
#define BATCH 4096
#define SPLINE_DIM 20
#define NQ 18   // knot intervals [t_m, t_m+1), m = 2..19

// Clamped knot vector T[23]: [-8]*3, +-2^k/32 ladder, 0, [8]*3
__device__ float d_T[23] = {
  -8.f, -8.f, -8.f, -4.f, -2.f, -1.f, -0.5f, -0.25f, -0.125f, -0.0625f,
  -0.03125f, 0.f, 0.03125f, 0.0625f, 0.125f, 0.25f, 0.5f, 1.f, 2.f, 4.f,
  8.f, 8.f, 8.f };

// ---------------------------------------------------------------------------
// Prep kernel:
//  (a) cs[(i*10+d)*1024 + slot] = (cos th, +-sin th), sign folded by the
//      slot's partner polarity (bit9 of logical index) at step d.
//      Slot bits: [r3 r2 r1 r0 | lane5..0]; logical bit b = slot bit (b-d)%10.
//  (b) qt[(i*18+mi)*512 + w] = (A,B,C,t_m): spline activation on interval
//      m=mi+2 is exactly the quadratic A + B*u + C*u^2, u = x - t_m.
//      Fit through 3 sample points with full Cox-de Boor in double.
// ---------------------------------------------------------------------------
__global__ void prep_kernel(const float* __restrict__ bp,
                            const float* __restrict__ sc,
                            float2* __restrict__ cs,
                            float4* __restrict__ qt) {
  int gid = blockIdx.x * 256 + threadIdx.x;
  if (gid < DEPTH * BDEPTH * 1024) {
    int slot = gid & 1023;
    int d = (gid >> 10) % BDEPTH;
    int i = gid / (BDEPTH * 1024);
    int n = 0;
#pragma unroll
    for (int b = 0; b < 10; ++b) {
      int src = b - d; if (src < 0) src += 10;
      n |= ((slot >> src) & 1) << b;
    }
    int pj = n & 511;
    float theta = bp[(i * HALF + pj) * BDEPTH + d];
    float c = cosf(theta), s = sinf(theta);
    cs[gid] = make_float2(c, (n & 512) ? -s : s);
  }
  int gid2 = gid - DEPTH * BDEPTH * 1024;
  if (gid2 >= 0 && gid2 < (DEPTH - 1) * NQ * HALF) {
    int w = gid2 & 511;
    int mi = (gid2 >> 9) % NQ;
    int i = gid2 / (NQ * HALF);
    int m = mi + 2;
    const float* cf = sc + (i * HALF + w) * SPLINE_DIM;
    double c0 = cf[mi], c1 = cf[mi + 1], c2 = cf[mi + 2];
    double tm1 = d_T[m - 1], tm = d_T[m], tp1 = d_T[m + 1], tp2 = d_T[m + 2];
    double h = tp1 - tm;
    double us[3] = { 0.0, 0.5 * h, 0.75 * h };
    double y[3];
#pragma unroll
    for (int k = 0; k < 3; ++k) {
      double x = tm + us[k];
      double left1 = x - tm, right1 = tp1 - x, left2 = x - tm1, right2 = tp2 - x;
      double inv1 = 1.0 / (tp1 - tm);
      double N0 = right1 * inv1, N1 = left1 * inv1;
      double temp0 = N0 / (tp1 - tm1);
      double B0 = right1 * temp0;
      double saved = left2 * temp0;
      double temp1 = N1 / (tp2 - tm);
      double B1 = right2 * temp1 + saved;
      double B2 = left1 * temp1;
      y[k] = c0 * B0 + c1 * B1 + c2 * B2;
    }
    double d1 = y[1] - y[0], d2 = y[2] - y[0];
    double u1 = us[1], u2 = us[2];
    double det = u1 * u2 * (u2 - u1);
    double Bq = (d1 * u2 * u2 - d2 * u1 * u1) / det;
    double Cq = (d2 * u1 - d1 * u2) / det;
    qt[gid2] = make_float4((float)y[0], (float)Bq, (float)Cq, (float)tm);
  }
}

// ---------------------------------------------------------------------------
// Compile-time lane shuffles: DPP for xor 1/2 (VALU pipe), ds_swizzle
// immediates for 4/8/16 (no addr calc), bpermute only for 32.
// ---------------------------------------------------------------------------
template <int M>
__device__ __forceinline__ float shfx(float x) {
  if constexpr (M == 1)
    return __int_as_float(__builtin_amdgcn_mov_dpp(__float_as_int(x), 0xB1, 0xF, 0xF, true));
  else if constexpr (M == 2)
    return __int_as_float(__builtin_amdgcn_mov_dpp(__float_as_int(x), 0x4E, 0xF, 0xF, true));
  else if constexpr (M == 4)
    return __int_as_float(__builtin_amdgcn_ds_swizzle(__float_as_int(x), 0x101F));
  else if constexpr (M == 8)
    return __int_as_float(__builtin_amdgcn_ds_swizzle(__float_as_int(x), 0x201F));
  else if constexpr (M == 16)
    return __int_as_float(__builtin_amdgcn_ds_swizzle(__float_as_int(x), 0x401F));
  else
    return __shfl_xor(x, 32, 64);
}

// Quadratic spline activation: interval-find via float exponent + 1 load + 2 fma.
__device__ __forceinline__ float qspline(float x, const float4* __restrict__ qL, int w) {
  x = fminf(fmaxf(x, -8.0f), 7.9999990f);
  float ax = fabsf(x);
  unsigned bits = __float_as_uint(ax);
  int e = (int)(bits >> 23) - 127;
  int ce = e + ((bits & 0x7fffffu) ? 1 : 0);
  int m = (x > 0.f) ? (17 + e) : (5 - ce);
  m = (ax < 0.03125f) ? ((x < 0.f) ? 10 : 11) : m;
  float4 qc = qL[(m - 2) * HALF + w];
  float u = x - qc.w;
  return fmaf(u, fmaf(u, qc.z, qc.y), qc.x);
}

// prefetch cs entries needed by step dd of layer L into buf (8 for dd<4, 16 else)
#define PF(buf, L, dd) do {                                                   \
    const float2* _p = cs + (L) * (BDEPTH * 1024) + (dd) * 1024 + lane;       \
    _Pragma("unroll") for (int r = 0; r < 16; ++r)                            \
      if ((dd) >= 4 || (r & (8 >> (dd))) == 0) buf[r] = _p[r * 64];           \
  } while (0)

// butterfly step dd<4: partner = reg ^ (8>>dd), same lane
#define CSTEP(buf, dd) do {                                                   \
    const int _mr = 8 >> (dd);                                                \
    _Pragma("unroll") for (int r = 0; r < 16; ++r)                            \
      if ((r & _mr) == 0) {                                                   \
        float2 v = buf[r];                                                    \
        float a0 = s0[r], b0 = s0[r + _mr];                                   \
        s0[r]       = fmaf(a0, v.x, b0 * v.y);                                \
        s0[r + _mr] = fmaf(b0, v.x, -(a0 * v.y));                             \
      }                                                                       \
  } while (0)

// butterfly step dd>=4: partner = lane ^ MM, same reg
#define LSTEP(buf, MM) do {                                                   \
    _Pragma("unroll") for (int r = 0; r < 16; ++r) {                          \
      float2 v = buf[r];                                                      \
      float p0 = shfx<MM>(s0[r]);                                             \
      s0[r] = fmaf(s0[r], v.x, p0 * v.y);                                     \
    }                                                                         \
  } while (0)

// ---------------------------------------------------------------------------
// Main kernel: ONE row per wave (16 regs of state). Steps 0-3 intra-lane reg
// pairs; steps 4-9 lane shuffles. cs table software-pipelined one step ahead
// through two explicitly alternating register buffers (no copies). Step 9
// prefetches the next layer's step 0, overlapping the spline phase.
// Barrier-free. 1024 blocks -> 4 blocks/CU -> 4 waves/SIMD.
// ---------------------------------------------------------------------------
__global__ __launch_bounds__(256, 4) void fwd_kernel(
    const float* __restrict__ X, const float2* __restrict__ cs,
    const float4* __restrict__ qt, float* __restrict__ out) {
  int tid = threadIdx.x;
  int lane = tid & 63;
  int wv = tid >> 6;                       // 0..3
  int row = blockIdx.x * 4 + wv;

  const float* xp = X + (long)row * NIN;
  float s0[16];
#pragma unroll
  for (int r = 0; r < 16; ++r) {
    int w = r * 64 + lane;
    s0[r] = (w < NIN) ? xp[w] : 0.f;
  }

  float2 A[16], B[16];
  PF(A, 0, 0);   // layer 0, step 0

  for (int i = 0; i < DEPTH; ++i) {
    PF(B, i, 1);  CSTEP(A, 0);
    PF(A, i, 2);  CSTEP(B, 1);
    PF(B, i, 3);  CSTEP(A, 2);
    PF(A, i, 4);  CSTEP(B, 3);
    PF(B, i, 5);  LSTEP(A, 32);
    PF(A, i, 6);  LSTEP(B, 16);
    PF(B, i, 7);  LSTEP(A, 8);
    PF(A, i, 8);  LSTEP(B, 4);
    PF(B, i, 9);  LSTEP(A, 2);
    if (i != DEPTH - 1) { PF(A, i + 1, 0); }
    LSTEP(B, 1);

    if (i != DEPTH - 1) {
      const float4* qL = qt + i * (NQ * HALF);
#pragma unroll
      for (int r = 8; r < 16; ++r) {
        int w = ((r - 8) << 6) | lane;
        s0[r - 8] += qspline(s0[r], qL, w);
      }
    }
  }

  float* op = out + (long)row * NIN;
#pragma unroll
  for (int r = 0; r < 13; ++r) {
    int w = r * 64 + lane;
    if (w < NIN) op[w] = s0[r];
  }
}

extern "C" void kernel_launch(void* const* d_in, const int* in_sizes, int n_in,
                              void* d_out, int out_size, void* d_ws, size_t ws_size,
                              hipStream_t stream) {
  const float* X  = (const float*)d_in[0];
  const float* bp = (const float*)d_in[1];   // [8,512,10]
  const float* sc = (const float*)d_in[2];   // [7,512,20]
  float* out = (float*)d_out;

  float2* cs = (float2*)d_ws;                                   // 655,360 B
  float4* qt = (float4*)((char*)d_ws + DEPTH * BDEPTH * 1024 * sizeof(float2)); // 1,032,192 B

  int prep_threads = DEPTH * BDEPTH * 1024 + (DEPTH - 1) * NQ * HALF; // 146,432
  prep_kernel<<<(prep_threads + 255) / 256, 256, 0, stream>>>(bp, sc, cs, qt);
  fwd_kernel<<<BATCH / 4, 256, 0, stream>>>(X, cs, qt, out);
}

// Round 5
// 145.080 us; speedup vs baseline: 1.0094x; 1.0094x over previous
//
#include <hip/hip_runtime.h>

#define NIN 784
#define WIDTH 1024
#define HALF 512
#define DEPTH 8
#define BDEPTH 10
#define BATCH 4096
#define SPLINE_DIM 20
#define NQ 18   // knot intervals [t_m, t_m+1), m = 2..19

// Clamped knot vector T[23]: [-8]*3, +-2^k/32 ladder, 0, [8]*3
__device__ float d_T[23] = {
  -8.f, -8.f, -8.f, -4.f, -2.f, -1.f, -0.5f, -0.25f, -0.125f, -0.0625f,
  -0.03125f, 0.f, 0.03125f, 0.0625f, 0.125f, 0.25f, 0.5f, 1.f, 2.f, 4.f,
  8.f, 8.f, 8.f };

// ---------------------------------------------------------------------------
// Prep kernel:
//  (a) cs[(i*10+d)*1024 + slot] = (cos th, +-sin th), sign folded by the
//      slot's partner polarity (bit9 of logical index) at step d.
//      Slot bits: [r3 r2 r1 r0 | lane5..0]; logical bit b = slot bit (b-d)%10.
//  (b) qt[(i*18+mi)*512 + w] = (A,B,C,t_m): spline activation on interval
//      m=mi+2 is exactly the quadratic A + B*u + C*u^2, u = x - t_m.
//      Fit through 3 sample points with full Cox-de Boor in double.
// ---------------------------------------------------------------------------
__global__ void prep_kernel(const float* __restrict__ bp,
                            const float* __restrict__ sc,
                            float2* __restrict__ cs,
                            float4* __restrict__ qt) {
  int gid = blockIdx.x * 256 + threadIdx.x;
  if (gid < DEPTH * BDEPTH * 1024) {
    int slot = gid & 1023;
    int d = (gid >> 10) % BDEPTH;
    int i = gid / (BDEPTH * 1024);
    int n = 0;
#pragma unroll
    for (int b = 0; b < 10; ++b) {
      int src = b - d; if (src < 0) src += 10;
      n |= ((slot >> src) & 1) << b;
    }
    int pj = n & 511;
    float theta = bp[(i * HALF + pj) * BDEPTH + d];
    float c = cosf(theta), s = sinf(theta);
    cs[gid] = make_float2(c, (n & 512) ? -s : s);
  }
  int gid2 = gid - DEPTH * BDEPTH * 1024;
  if (gid2 >= 0 && gid2 < (DEPTH - 1) * NQ * HALF) {
    int w = gid2 & 511;
    int mi = (gid2 >> 9) % NQ;
    int i = gid2 / (NQ * HALF);
    int m = mi + 2;
    const float* cf = sc + (i * HALF + w) * SPLINE_DIM;
    double c0 = cf[mi], c1 = cf[mi + 1], c2 = cf[mi + 2];
    double tm1 = d_T[m - 1], tm = d_T[m], tp1 = d_T[m + 1], tp2 = d_T[m + 2];
    double h = tp1 - tm;
    double us[3] = { 0.0, 0.5 * h, 0.75 * h };
    double y[3];
#pragma unroll
    for (int k = 0; k < 3; ++k) {
      double x = tm + us[k];
      double left1 = x - tm, right1 = tp1 - x, left2 = x - tm1, right2 = tp2 - x;
      double inv1 = 1.0 / (tp1 - tm);
      double N0 = right1 * inv1, N1 = left1 * inv1;
      double temp0 = N0 / (tp1 - tm1);
      double B0 = right1 * temp0;
      double saved = left2 * temp0;
      double temp1 = N1 / (tp2 - tm);
      double B1 = right2 * temp1 + saved;
      double B2 = left1 * temp1;
      y[k] = c0 * B0 + c1 * B1 + c2 * B2;
    }
    double d1 = y[1] - y[0], d2 = y[2] - y[0];
    double u1 = us[1], u2 = us[2];
    double det = u1 * u2 * (u2 - u1);
    double Bq = (d1 * u2 * u2 - d2 * u1 * u1) / det;
    double Cq = (d2 * u1 - d1 * u2) / det;
    qt[gid2] = make_float4((float)y[0], (float)Bq, (float)Cq, (float)tm);
  }
}

// ---------------------------------------------------------------------------
// Compile-time lane shuffles: DPP for xor 1/2 (VALU pipe), ds_swizzle
// immediates for 4/8/16 (no addr calc), bpermute only for 32.
// ---------------------------------------------------------------------------
template <int M>
__device__ __forceinline__ float shfx(float x) {
  if constexpr (M == 1)
    return __int_as_float(__builtin_amdgcn_mov_dpp(__float_as_int(x), 0xB1, 0xF, 0xF, true));
  else if constexpr (M == 2)
    return __int_as_float(__builtin_amdgcn_mov_dpp(__float_as_int(x), 0x4E, 0xF, 0xF, true));
  else if constexpr (M == 4)
    return __int_as_float(__builtin_amdgcn_ds_swizzle(__float_as_int(x), 0x101F));
  else if constexpr (M == 8)
    return __int_as_float(__builtin_amdgcn_ds_swizzle(__float_as_int(x), 0x201F));
  else if constexpr (M == 16)
    return __int_as_float(__builtin_amdgcn_ds_swizzle(__float_as_int(x), 0x401F));
  else
    return __shfl_xor(x, 32, 64);
}

// Quadratic spline activation: interval-find via float exponent + 1 load + 2 fma.
__device__ __forceinline__ float qspline(float x, const float4* __restrict__ qL, int w) {
  x = fminf(fmaxf(x, -8.0f), 7.9999990f);
  float ax = fabsf(x);
  unsigned bits = __float_as_uint(ax);
  int e = (int)(bits >> 23) - 127;
  int ce = e + ((bits & 0x7fffffu) ? 1 : 0);
  int m = (x > 0.f) ? (17 + e) : (5 - ce);
  m = (ax < 0.03125f) ? ((x < 0.f) ? 10 : 11) : m;
  float4 qc = qL[(m - 2) * HALF + w];
  float u = x - qc.w;
  return fmaf(u, fmaf(u, qc.z, qc.y), qc.x);
}

// prefetch cs entries needed by step dd of layer L into buf (8 for dd<4, 16 else)
#define PF(buf, L, dd) do {                                                   \
    const float2* _p = cs + (L) * (BDEPTH * 1024) + (dd) * 1024 + lane;       \
    _Pragma("unroll") for (int r = 0; r < 16; ++r)                            \
      if ((dd) >= 4 || (r & (8 >> (dd))) == 0) buf[r] = _p[r * 64];           \
  } while (0)

// butterfly step dd<4: partner = reg ^ (8>>dd), same lane
#define CSTEP(buf, dd) do {                                                   \
    const int _mr = 8 >> (dd);                                                \
    _Pragma("unroll") for (int r = 0; r < 16; ++r)                            \
      if ((r & _mr) == 0) {                                                   \
        float2 v = buf[r];                                                    \
        float a0 = s0[r], b0 = s0[r + _mr];                                   \
        s0[r]       = fmaf(a0, v.x, b0 * v.y);                                \
        s0[r + _mr] = fmaf(b0, v.x, -(a0 * v.y));                             \
      }                                                                       \
  } while (0)

// butterfly step dd>=4: partner = lane ^ MM, same reg
#define LSTEP(buf, MM) do {                                                   \
    _Pragma("unroll") for (int r = 0; r < 16; ++r) {                          \
      float2 v = buf[r];                                                      \
      float p0 = shfx<MM>(s0[r]);                                             \
      s0[r] = fmaf(s0[r], v.x, p0 * v.y);                                     \
    }                                                                         \
  } while (0)

// ---------------------------------------------------------------------------
// Main kernel: ONE row per wave (16 regs of state). Steps 0-3 intra-lane reg
// pairs; steps 4-9 lane shuffles. cs table software-pipelined one step ahead
// through two explicitly alternating register buffers (no copies). Step 9
// prefetches the next layer's step 0, overlapping the spline phase.
// Barrier-free. 1024 blocks; RELAXED register cap (256) so the allocator
// lands ~90-110 VGPRs -> hardware occupancy tier 65..128 -> 4 waves/SIMD
// with NO spill (the (256,4) bound clamped to 64 VGPRs and spilled).
// ---------------------------------------------------------------------------
__global__ __launch_bounds__(256, 2) void fwd_kernel(
    const float* __restrict__ X, const float2* __restrict__ cs,
    const float4* __restrict__ qt, float* __restrict__ out) {
  int tid = threadIdx.x;
  int lane = tid & 63;
  int wv = tid >> 6;                       // 0..3
  int row = blockIdx.x * 4 + wv;

  const float* xp = X + (long)row * NIN;
  float s0[16];
#pragma unroll
  for (int r = 0; r < 16; ++r) {
    int w = r * 64 + lane;
    s0[r] = (w < NIN) ? xp[w] : 0.f;
  }

  float2 A[16], B[16];
  PF(A, 0, 0);   // layer 0, step 0

  for (int i = 0; i < DEPTH; ++i) {
    PF(B, i, 1);  CSTEP(A, 0);
    PF(A, i, 2);  CSTEP(B, 1);
    PF(B, i, 3);  CSTEP(A, 2);
    PF(A, i, 4);  CSTEP(B, 3);
    PF(B, i, 5);  LSTEP(A, 32);
    PF(A, i, 6);  LSTEP(B, 16);
    PF(B, i, 7);  LSTEP(A, 8);
    PF(A, i, 8);  LSTEP(B, 4);
    PF(B, i, 9);  LSTEP(A, 2);
    if (i != DEPTH - 1) { PF(A, i + 1, 0); }
    LSTEP(B, 1);

    if (i != DEPTH - 1) {
      const float4* qL = qt + i * (NQ * HALF);
#pragma unroll
      for (int r = 8; r < 16; ++r) {
        int w = ((r - 8) << 6) | lane;
        s0[r - 8] += qspline(s0[r], qL, w);
      }
    }
  }

  float* op = out + (long)row * NIN;
#pragma unroll
  for (int r = 0; r < 13; ++r) {
    int w = r * 64 + lane;
    if (w < NIN) op[w] = s0[r];
  }
}

extern "C" void kernel_launch(void* const* d_in, const int* in_sizes, int n_in,
                              void* d_out, int out_size, void* d_ws, size_t ws_size,
                              hipStream_t stream) {
  const float* X  = (const float*)d_in[0];
  const float* bp = (const float*)d_in[1];   // [8,512,10]
  const float* sc = (const float*)d_in[2];   // [7,512,20]
  float* out = (float*)d_out;

  float2* cs = (float2*)d_ws;                                   // 655,360 B
  float4* qt = (float4*)((char*)d_ws + DEPTH * BDEPTH * 1024 * sizeof(float2)); // 1,032,192 B

  int prep_threads = DEPTH * BDEPTH * 1024 + (DEPTH - 1) * NQ * HALF; // 146,432
  prep_kernel<<<(prep_threads + 255) / 256, 256, 0, stream>>>(bp, sc, cs, qt);
  fwd_kernel<<<BATCH / 4, 256, 0, stream>>>(X, cs, qt, out);
}

// Round 6
// 92.853 us; speedup vs baseline: 1.5771x; 1.5625x over previous
//
#include <hip/hip_runtime.h>

#define NIN 784
#define WIDTH 1024
#define HALF 512
#define DEPTH 8
#define BDEPTH 10
#define BATCH 4096
#define SPLINE_DIM 20
#define NQ 18   // knot intervals [t_m, t_m+1), m = 2..19

// Clamped knot vector T[23]: [-8]*3, +-2^k/32 ladder, 0, [8]*3
__device__ float d_T[23] = {
  -8.f, -8.f, -8.f, -4.f, -2.f, -1.f, -0.5f, -0.25f, -0.125f, -0.0625f,
  -0.03125f, 0.f, 0.03125f, 0.0625f, 0.125f, 0.25f, 0.5f, 1.f, 2.f, 4.f,
  8.f, 8.f, 8.f };

// ---------------------------------------------------------------------------
// Prep kernel:
//  (a) cs[(i*10+d)*1024 + slot] = (cos th, +-sin th), sign folded by the
//      slot's partner polarity (bit9 of logical index) at step d.
//      Slot bits: [r3 r2 r1 r0 | lane5..0]; logical bit b = slot bit (b-d)%10.
//  (b) qt[(i*18+mi)*512 + w] = (A,B,C,t_m): spline activation on interval
//      m=mi+2 is exactly the quadratic A + B*u + C*u^2, u = x - t_m.
// ---------------------------------------------------------------------------
__global__ void prep_kernel(const float* __restrict__ bp,
                            const float* __restrict__ sc,
                            float2* __restrict__ cs,
                            float4* __restrict__ qt) {
  int gid = blockIdx.x * 256 + threadIdx.x;
  if (gid < DEPTH * BDEPTH * 1024) {
    int slot = gid & 1023;
    int d = (gid >> 10) % BDEPTH;
    int i = gid / (BDEPTH * 1024);
    int n = 0;
#pragma unroll
    for (int b = 0; b < 10; ++b) {
      int src = b - d; if (src < 0) src += 10;
      n |= ((slot >> src) & 1) << b;
    }
    int pj = n & 511;
    float theta = bp[(i * HALF + pj) * BDEPTH + d];
    float c = cosf(theta), s = sinf(theta);
    cs[gid] = make_float2(c, (n & 512) ? -s : s);
  }
  int gid2 = gid - DEPTH * BDEPTH * 1024;
  if (gid2 >= 0 && gid2 < (DEPTH - 1) * NQ * HALF) {
    int w = gid2 & 511;
    int mi = (gid2 >> 9) % NQ;
    int i = gid2 / (NQ * HALF);
    int m = mi + 2;
    const float* cf = sc + (i * HALF + w) * SPLINE_DIM;
    double c0 = cf[mi], c1 = cf[mi + 1], c2 = cf[mi + 2];
    double tm1 = d_T[m - 1], tm = d_T[m], tp1 = d_T[m + 1], tp2 = d_T[m + 2];
    double h = tp1 - tm;
    double us[3] = { 0.0, 0.5 * h, 0.75 * h };
    double y[3];
#pragma unroll
    for (int k = 0; k < 3; ++k) {
      double x = tm + us[k];
      double left1 = x - tm, right1 = tp1 - x, left2 = x - tm1, right2 = tp2 - x;
      double inv1 = 1.0 / (tp1 - tm);
      double N0 = right1 * inv1, N1 = left1 * inv1;
      double temp0 = N0 / (tp1 - tm1);
      double B0 = right1 * temp0;
      double saved = left2 * temp0;
      double temp1 = N1 / (tp2 - tm);
      double B1 = right2 * temp1 + saved;
      double B2 = left1 * temp1;
      y[k] = c0 * B0 + c1 * B1 + c2 * B2;
    }
    double d1 = y[1] - y[0], d2 = y[2] - y[0];
    double u1 = us[1], u2 = us[2];
    double det = u1 * u2 * (u2 - u1);
    double Bq = (d1 * u2 * u2 - d2 * u1 * u1) / det;
    double Cq = (d2 * u1 - d1 * u2) / det;
    qt[gid2] = make_float4((float)y[0], (float)Bq, (float)Cq, (float)tm);
  }
}

// ---------------------------------------------------------------------------
// Compile-time lane shuffles: DPP for xor 1/2 (VALU pipe), ds_swizzle
// immediates for 4/8/16 (no addr calc), bpermute only for 32.
// ---------------------------------------------------------------------------
template <int M>
__device__ __forceinline__ float shfx(float x) {
  if constexpr (M == 1)
    return __int_as_float(__builtin_amdgcn_mov_dpp(__float_as_int(x), 0xB1, 0xF, 0xF, true));
  else if constexpr (M == 2)
    return __int_as_float(__builtin_amdgcn_mov_dpp(__float_as_int(x), 0x4E, 0xF, 0xF, true));
  else if constexpr (M == 4)
    return __int_as_float(__builtin_amdgcn_ds_swizzle(__float_as_int(x), 0x101F));
  else if constexpr (M == 8)
    return __int_as_float(__builtin_amdgcn_ds_swizzle(__float_as_int(x), 0x201F));
  else if constexpr (M == 16)
    return __int_as_float(__builtin_amdgcn_ds_swizzle(__float_as_int(x), 0x401F));
  else
    return __shfl_xor(x, 32, 64);
}

// Quadratic spline activation: interval-find via float exponent + 1 load + 2 fma.
__device__ __forceinline__ float qspline(float x, const float4* __restrict__ qL, int w) {
  x = fminf(fmaxf(x, -8.0f), 7.9999990f);
  float ax = fabsf(x);
  unsigned bits = __float_as_uint(ax);
  int e = (int)(bits >> 23) - 127;
  int ce = e + ((bits & 0x7fffffu) ? 1 : 0);
  int m = (x > 0.f) ? (17 + e) : (5 - ce);
  m = (ax < 0.03125f) ? ((x < 0.f) ? 10 : 11) : m;
  float4 qc = qL[(m - 2) * HALF + w];
  float u = x - qc.w;
  return fmaf(u, fmaf(u, qc.z, qc.y), qc.x);
}

// prefetch cs entries needed by step dd of layer csL into buf (8 for dd<4, 16 else)
#define PF(buf, dd) do {                                                      \
    const float2* _p = csL + (dd) * 1024 + lane;                              \
    _Pragma("unroll") for (int r = 0; r < 16; ++r)                            \
      if ((dd) >= 4 || (r & (8 >> (dd))) == 0) buf[r] = _p[r * 64];           \
  } while (0)

// prefetch next layer's step 0
#define PFN(buf) do {                                                         \
    const float2* _p = csL + BDEPTH * 1024 + lane;                            \
    _Pragma("unroll") for (int r = 0; r < 16; ++r)                            \
      if ((r & 8) == 0) buf[r] = _p[r * 64];                                  \
  } while (0)

// butterfly step dd<4: partner = reg ^ (8>>dd), same lane
#define CSTEP(buf, dd) do {                                                   \
    const int _mr = 8 >> (dd);                                                \
    _Pragma("unroll") for (int r = 0; r < 16; ++r)                            \
      if ((r & _mr) == 0) {                                                   \
        float2 v = buf[r];                                                    \
        float a0 = s0[r], b0 = s0[r + _mr];                                   \
        s0[r]       = fmaf(a0, v.x, b0 * v.y);                                \
        s0[r + _mr] = fmaf(b0, v.x, -(a0 * v.y));                             \
        float a1 = s1[r], b1 = s1[r + _mr];                                   \
        s1[r]       = fmaf(a1, v.x, b1 * v.y);                                \
        s1[r + _mr] = fmaf(b1, v.x, -(a1 * v.y));                             \
      }                                                                       \
  } while (0)

// butterfly step dd>=4: partner = lane ^ MM, same reg
#define LSTEP(buf, MM) do {                                                   \
    _Pragma("unroll") for (int r = 0; r < 16; ++r) {                          \
      float2 v = buf[r];                                                      \
      float p0 = shfx<MM>(s0[r]);                                             \
      float p1 = shfx<MM>(s1[r]);                                             \
      s0[r] = fmaf(s0[r], v.x, p0 * v.y);                                     \
      s1[r] = fmaf(s1[r], v.x, p1 * v.y);                                     \
    }                                                                         \
  } while (0)

// ---------------------------------------------------------------------------
// Main kernel: 2 rows per wave (R3 geometry). Layer loop FORCED ROLLED
// (#pragma unroll 1): per-layer body ~10 KB of code fits the 32 KB I$, hot
// from layer 1 on. (The fully-unrolled version was ~80 KB of straight-line
// code -> permanent I-fetch streaming from L2; suspected dominant stall.)
// Steps 0-3 intra-lane reg pairs; steps 4-9 lane shuffles; cs table
// software-pipelined one step ahead through alternating A/B reg buffers.
// ---------------------------------------------------------------------------
__global__ __launch_bounds__(256, 2) void fwd_kernel(
    const float* __restrict__ X, const float2* __restrict__ cs,
    const float4* __restrict__ qt, float* __restrict__ out) {
  int tid = threadIdx.x;
  int lane = tid & 63;
  int wv = tid >> 6;                       // 0..3
  int row0 = blockIdx.x * 8 + wv * 2;

  const float* x0p = X + (long)row0 * NIN;
  const float* x1p = X + (long)(row0 + 1) * NIN;
  float s0[16], s1[16];
#pragma unroll
  for (int r = 0; r < 16; ++r) {
    int w = r * 64 + lane;
    bool in = (w < NIN);
    s0[r] = in ? x0p[w] : 0.f;
    s1[r] = in ? x1p[w] : 0.f;
  }

  float2 A[16], B[16];
  {
    const float2* csL = cs;
    PF(A, 0);   // layer 0, step 0
  }

#pragma unroll 1
  for (int i = 0; i < DEPTH; ++i) {
    const float2* csL = cs + i * (BDEPTH * 1024);
    PF(B, 1);  CSTEP(A, 0);
    PF(A, 2);  CSTEP(B, 1);
    PF(B, 3);  CSTEP(A, 2);
    PF(A, 4);  CSTEP(B, 3);
    PF(B, 5);  LSTEP(A, 32);
    PF(A, 6);  LSTEP(B, 16);
    PF(B, 7);  LSTEP(A, 8);
    PF(A, 8);  LSTEP(B, 4);
    PF(B, 9);  LSTEP(A, 2);
    if (i != DEPTH - 1) { PFN(A); }
    LSTEP(B, 1);

    if (i != DEPTH - 1) {
      const float4* qL = qt + i * (NQ * HALF);
#pragma unroll
      for (int r = 8; r < 16; ++r) {
        int w = ((r - 8) << 6) | lane;
        s0[r - 8] += qspline(s0[r], qL, w);
        s1[r - 8] += qspline(s1[r], qL, w);
      }
    }
  }

  float* o0 = out + (long)row0 * NIN;
  float* o1 = out + (long)(row0 + 1) * NIN;
#pragma unroll
  for (int r = 0; r < 13; ++r) {
    int w = r * 64 + lane;
    if (w < NIN) { o0[w] = s0[r]; o1[w] = s1[r]; }
  }
}

extern "C" void kernel_launch(void* const* d_in, const int* in_sizes, int n_in,
                              void* d_out, int out_size, void* d_ws, size_t ws_size,
                              hipStream_t stream) {
  const float* X  = (const float*)d_in[0];
  const float* bp = (const float*)d_in[1];   // [8,512,10]
  const float* sc = (const float*)d_in[2];   // [7,512,20]
  float* out = (float*)d_out;

  float2* cs = (float2*)d_ws;                                   // 655,360 B
  float4* qt = (float4*)((char*)d_ws + DEPTH * BDEPTH * 1024 * sizeof(float2)); // 1,032,192 B

  int prep_threads = DEPTH * BDEPTH * 1024 + (DEPTH - 1) * NQ * HALF; // 146,432
  prep_kernel<<<(prep_threads + 255) / 256, 256, 0, stream>>>(bp, sc, cs, qt);
  fwd_kernel<<<BATCH / 8, 256, 0, stream>>>(X, cs, qt, out);
}

// Round 7
// 78.104 us; speedup vs baseline: 1.8749x; 1.1888x over previous
//
#include <hip/hip_runtime.h>

#define NIN 784
#define WIDTH 1024
#define HALF 512
#define DEPTH 8
#define BDEPTH 10
#define BATCH 4096
#define SPLINE_DIM 20
#define NQ 18   // knot intervals [t_m, t_m+1), m = 2..19

// Clamped knot vector T[23]: [-8]*3, +-2^k/32 ladder, 0, [8]*3
__device__ float d_T[23] = {
  -8.f, -8.f, -8.f, -4.f, -2.f, -1.f, -0.5f, -0.25f, -0.125f, -0.0625f,
  -0.03125f, 0.f, 0.03125f, 0.0625f, 0.125f, 0.25f, 0.5f, 1.f, 2.f, 4.f,
  8.f, 8.f, 8.f };

// ---------------------------------------------------------------------------
// Prep kernel:
//  (a) cs[(i*10+d)*1024 + slot] = (cos th, +-sin th), sign folded by the
//      slot's partner polarity (bit9 of logical index) at step d.
//      Slot bits: [r3 r2 r1 r0 | lane5..0]; logical bit b = slot bit (b-d)%10.
//  (b) qt[(i*18+mi)*512 + w] = (A,B,C,t_m): spline activation on interval
//      m=mi+2 is exactly the quadratic A + B*u + C*u^2, u = x - t_m.
// ---------------------------------------------------------------------------
__global__ void prep_kernel(const float* __restrict__ bp,
                            const float* __restrict__ sc,
                            float2* __restrict__ cs,
                            float4* __restrict__ qt) {
  int gid = blockIdx.x * 256 + threadIdx.x;
  if (gid < DEPTH * BDEPTH * 1024) {
    int slot = gid & 1023;
    int d = (gid >> 10) % BDEPTH;
    int i = gid / (BDEPTH * 1024);
    int n = 0;
#pragma unroll
    for (int b = 0; b < 10; ++b) {
      int src = b - d; if (src < 0) src += 10;
      n |= ((slot >> src) & 1) << b;
    }
    int pj = n & 511;
    float theta = bp[(i * HALF + pj) * BDEPTH + d];
    float c = cosf(theta), s = sinf(theta);
    cs[gid] = make_float2(c, (n & 512) ? -s : s);
  }
  int gid2 = gid - DEPTH * BDEPTH * 1024;
  if (gid2 >= 0 && gid2 < (DEPTH - 1) * NQ * HALF) {
    int w = gid2 & 511;
    int mi = (gid2 >> 9) % NQ;
    int i = gid2 / (NQ * HALF);
    int m = mi + 2;
    const float* cf = sc + (i * HALF + w) * SPLINE_DIM;
    double c0 = cf[mi], c1 = cf[mi + 1], c2 = cf[mi + 2];
    double tm1 = d_T[m - 1], tm = d_T[m], tp1 = d_T[m + 1], tp2 = d_T[m + 2];
    double h = tp1 - tm;
    double us[3] = { 0.0, 0.5 * h, 0.75 * h };
    double y[3];
#pragma unroll
    for (int k = 0; k < 3; ++k) {
      double x = tm + us[k];
      double left1 = x - tm, right1 = tp1 - x, left2 = x - tm1, right2 = tp2 - x;
      double inv1 = 1.0 / (tp1 - tm);
      double N0 = right1 * inv1, N1 = left1 * inv1;
      double temp0 = N0 / (tp1 - tm1);
      double B0 = right1 * temp0;
      double saved = left2 * temp0;
      double temp1 = N1 / (tp2 - tm);
      double B1 = right2 * temp1 + saved;
      double B2 = left1 * temp1;
      y[k] = c0 * B0 + c1 * B1 + c2 * B2;
    }
    double d1 = y[1] - y[0], d2 = y[2] - y[0];
    double u1 = us[1], u2 = us[2];
    double det = u1 * u2 * (u2 - u1);
    double Bq = (d1 * u2 * u2 - d2 * u1 * u1) / det;
    double Cq = (d2 * u1 - d1 * u2) / det;
    qt[gid2] = make_float4((float)y[0], (float)Bq, (float)Cq, (float)tm);
  }
}

// ---------------------------------------------------------------------------
// Compile-time lane shuffles: DPP for xor 1/2 (VALU pipe), ds_swizzle
// immediates for 4/8/16 (no addr calc), bpermute only for 32.
// ---------------------------------------------------------------------------
template <int M>
__device__ __forceinline__ float shfx(float x) {
  if constexpr (M == 1)
    return __int_as_float(__builtin_amdgcn_mov_dpp(__float_as_int(x), 0xB1, 0xF, 0xF, true));
  else if constexpr (M == 2)
    return __int_as_float(__builtin_amdgcn_mov_dpp(__float_as_int(x), 0x4E, 0xF, 0xF, true));
  else if constexpr (M == 4)
    return __int_as_float(__builtin_amdgcn_ds_swizzle(__float_as_int(x), 0x101F));
  else if constexpr (M == 8)
    return __int_as_float(__builtin_amdgcn_ds_swizzle(__float_as_int(x), 0x201F));
  else if constexpr (M == 16)
    return __int_as_float(__builtin_amdgcn_ds_swizzle(__float_as_int(x), 0x401F));
  else
    return __shfl_xor(x, 32, 64);
}

// Quadratic spline activation: interval-find via float exponent + 1 load + 2 fma.
__device__ __forceinline__ float qspline(float x, const float4* __restrict__ qL, int w) {
  x = fminf(fmaxf(x, -8.0f), 7.9999990f);
  float ax = fabsf(x);
  unsigned bits = __float_as_uint(ax);
  int e = (int)(bits >> 23) - 127;
  int ce = e + ((bits & 0x7fffffu) ? 1 : 0);
  int m = (x > 0.f) ? (17 + e) : (5 - ce);
  m = (ax < 0.03125f) ? ((x < 0.f) ? 10 : 11) : m;
  float4 qc = qL[(m - 2) * HALF + w];
  float u = x - qc.w;
  return fmaf(u, fmaf(u, qc.z, qc.y), qc.x);
}

// Cooperative stage of 5 steps' tables (5*1024 float2 = 40 KB) into LDS.
// 2560 float4 / 256 threads = 10 independent dwordx4 per thread, coalesced.
#define STAGE(off5) do {                                                      \
    const float4* _src = (const float4*)(csL + (off5) * 1024);                \
    float4* _dst = (float4*)csS;                                              \
    _Pragma("unroll") for (int k = 0; k < 10; ++k)                            \
      _dst[tid + k * 256] = _src[tid + k * 256];                              \
  } while (0)

// butterfly step dd<4 from LDS slot sl: partner = reg ^ (8>>dd), same lane
#define CSTEPL(sl, dd) do {                                                   \
    const int _mr = 8 >> (dd);                                                \
    _Pragma("unroll") for (int r = 0; r < 16; ++r)                            \
      if ((r & _mr) == 0) {                                                   \
        float2 v = csS[(sl) * 1024 + r * 64 + lane];                          \
        float a0 = s0[r], b0 = s0[r + _mr];                                   \
        s0[r]       = fmaf(a0, v.x, b0 * v.y);                                \
        s0[r + _mr] = fmaf(b0, v.x, -(a0 * v.y));                             \
        float a1 = s1[r], b1 = s1[r + _mr];                                   \
        s1[r]       = fmaf(a1, v.x, b1 * v.y);                                \
        s1[r + _mr] = fmaf(b1, v.x, -(a1 * v.y));                             \
      }                                                                       \
  } while (0)

// butterfly step dd>=4 from LDS slot sl: partner = lane ^ MM, same reg
#define LSTEPL(sl, MM) do {                                                   \
    _Pragma("unroll") for (int r = 0; r < 16; ++r) {                          \
      float2 v = csS[(sl) * 1024 + r * 64 + lane];                            \
      float p0 = shfx<MM>(s0[r]);                                             \
      float p1 = shfx<MM>(s1[r]);                                             \
      s0[r] = fmaf(s0[r], v.x, p0 * v.y);                                     \
      s1[r] = fmaf(s1[r], v.x, p1 * v.y);                                     \
    }                                                                         \
  } while (0)

// ---------------------------------------------------------------------------
// Main kernel: 2 rows per wave; the cs table is staged into LDS once per
// BLOCK (4 waves share it) in 5-step chunks of 40 KB. Per-wave VMEM issue
// drops ~8x (1280 -> 160 instrs) and step-table reads become short-latency
// ds_read_b64 (2-way bank aliasing = free). Steps 0-3 intra-lane reg pairs;
// steps 4-9 lane shuffles. Layer loop rolled (code fits I$).
// ---------------------------------------------------------------------------
__global__ __launch_bounds__(256, 2) void fwd_kernel(
    const float* __restrict__ X, const float2* __restrict__ cs,
    const float4* __restrict__ qt, float* __restrict__ out) {
  __shared__ float2 csS[5 * 1024];   // 40 KB
  int tid = threadIdx.x;
  int lane = tid & 63;
  int wv = tid >> 6;                       // 0..3
  int row0 = blockIdx.x * 8 + wv * 2;

  const float* x0p = X + (long)row0 * NIN;
  const float* x1p = X + (long)(row0 + 1) * NIN;
  float s0[16], s1[16];
#pragma unroll
  for (int r = 0; r < 16; ++r) {
    int w = r * 64 + lane;
    bool in = (w < NIN);
    s0[r] = in ? x0p[w] : 0.f;
    s1[r] = in ? x1p[w] : 0.f;
  }

#pragma unroll 1
  for (int i = 0; i < DEPTH; ++i) {
    const float2* csL = cs + i * (BDEPTH * 1024);

    __syncthreads();               // prior half consumed
    STAGE(0);                      // steps 0..4
    __syncthreads();
    CSTEPL(0, 0);
    CSTEPL(1, 1);
    CSTEPL(2, 2);
    CSTEPL(3, 3);
    LSTEPL(4, 32);

    __syncthreads();               // half consumed
    STAGE(5);                      // steps 5..9
    __syncthreads();
    LSTEPL(0, 16);
    LSTEPL(1, 8);
    LSTEPL(2, 4);
    LSTEPL(3, 2);
    LSTEPL(4, 1);

    if (i != DEPTH - 1) {
      const float4* qL = qt + i * (NQ * HALF);
#pragma unroll
      for (int r = 8; r < 16; ++r) {
        int w = ((r - 8) << 6) | lane;
        s0[r - 8] += qspline(s0[r], qL, w);
        s1[r - 8] += qspline(s1[r], qL, w);
      }
    }
  }

  float* o0 = out + (long)row0 * NIN;
  float* o1 = out + (long)(row0 + 1) * NIN;
#pragma unroll
  for (int r = 0; r < 13; ++r) {
    int w = r * 64 + lane;
    if (w < NIN) { o0[w] = s0[r]; o1[w] = s1[r]; }
  }
}

extern "C" void kernel_launch(void* const* d_in, const int* in_sizes, int n_in,
                              void* d_out, int out_size, void* d_ws, size_t ws_size,
                              hipStream_t stream) {
  const float* X  = (const float*)d_in[0];
  const float* bp = (const float*)d_in[1];   // [8,512,10]
  const float* sc = (const float*)d_in[2];   // [7,512,20]
  float* out = (float*)d_out;

  float2* cs = (float2*)d_ws;                                   // 655,360 B
  float4* qt = (float4*)((char*)d_ws + DEPTH * BDEPTH * 1024 * sizeof(float2)); // 1,032,192 B

  int prep_threads = DEPTH * BDEPTH * 1024 + (DEPTH - 1) * NQ * HALF; // 146,432
  prep_kernel<<<(prep_threads + 255) / 256, 256, 0, stream>>>(bp, sc, cs, qt);
  fwd_kernel<<<BATCH / 8, 256, 0, stream>>>(X, cs, qt, out);
}

// Round 8
// 77.945 us; speedup vs baseline: 1.8788x; 1.0020x over previous
//
#include <hip/hip_runtime.h>

#define NIN 784
#define WIDTH 1024
#define HALF 512
#define DEPTH 8
#define BDEPTH 10
#define BATCH 4096
#define SPLINE_DIM 20
#define NQ 18   // knot intervals [t_m, t_m+1), m = 2..19

// Clamped knot vector T[23]: [-8]*3, +-2^k/32 ladder, 0, [8]*3
__device__ float d_T[23] = {
  -8.f, -8.f, -8.f, -4.f, -2.f, -1.f, -0.5f, -0.25f, -0.125f, -0.0625f,
  -0.03125f, 0.f, 0.03125f, 0.0625f, 0.125f, 0.25f, 0.5f, 1.f, 2.f, 4.f,
  8.f, 8.f, 8.f };

// ---------------------------------------------------------------------------
// Prep kernel:
//  (a) cs[(i*10+d)*1024 + slot] = (cos th, +-sin th), sign folded by the
//      slot's partner polarity (bit9 of logical index) at step d.
//      Slot bits: [r3 r2 r1 r0 | lane5..0]; logical bit b = slot bit (b-d)%10.
//  (b) qt[(i*18+mi)*512 + w] = (A,B,C,t_m): spline activation on interval
//      m=mi+2 is exactly the quadratic A + B*u + C*u^2, u = x - t_m.
// ---------------------------------------------------------------------------
__global__ void prep_kernel(const float* __restrict__ bp,
                            const float* __restrict__ sc,
                            float2* __restrict__ cs,
                            float4* __restrict__ qt) {
  int gid = blockIdx.x * 256 + threadIdx.x;
  if (gid < DEPTH * BDEPTH * 1024) {
    int slot = gid & 1023;
    int d = (gid >> 10) % BDEPTH;
    int i = gid / (BDEPTH * 1024);
    int n = 0;
#pragma unroll
    for (int b = 0; b < 10; ++b) {
      int src = b - d; if (src < 0) src += 10;
      n |= ((slot >> src) & 1) << b;
    }
    int pj = n & 511;
    float theta = bp[(i * HALF + pj) * BDEPTH + d];
    float c = cosf(theta), s = sinf(theta);
    cs[gid] = make_float2(c, (n & 512) ? -s : s);
  }
  int gid2 = gid - DEPTH * BDEPTH * 1024;
  if (gid2 >= 0 && gid2 < (DEPTH - 1) * NQ * HALF) {
    int w = gid2 & 511;
    int mi = (gid2 >> 9) % NQ;
    int i = gid2 / (NQ * HALF);
    int m = mi + 2;
    const float* cf = sc + (i * HALF + w) * SPLINE_DIM;
    double c0 = cf[mi], c1 = cf[mi + 1], c2 = cf[mi + 2];
    double tm1 = d_T[m - 1], tm = d_T[m], tp1 = d_T[m + 1], tp2 = d_T[m + 2];
    double h = tp1 - tm;
    double us[3] = { 0.0, 0.5 * h, 0.75 * h };
    double y[3];
#pragma unroll
    for (int k = 0; k < 3; ++k) {
      double x = tm + us[k];
      double left1 = x - tm, right1 = tp1 - x, left2 = x - tm1, right2 = tp2 - x;
      double inv1 = 1.0 / (tp1 - tm);
      double N0 = right1 * inv1, N1 = left1 * inv1;
      double temp0 = N0 / (tp1 - tm1);
      double B0 = right1 * temp0;
      double saved = left2 * temp0;
      double temp1 = N1 / (tp2 - tm);
      double B1 = right2 * temp1 + saved;
      double B2 = left1 * temp1;
      y[k] = c0 * B0 + c1 * B1 + c2 * B2;
    }
    double d1 = y[1] - y[0], d2 = y[2] - y[0];
    double u1 = us[1], u2 = us[2];
    double det = u1 * u2 * (u2 - u1);
    double Bq = (d1 * u2 * u2 - d2 * u1 * u1) / det;
    double Cq = (d2 * u1 - d1 * u2) / det;
    qt[gid2] = make_float4((float)y[0], (float)Bq, (float)Cq, (float)tm);
  }
}

// ---------------------------------------------------------------------------
// Compile-time lane shuffles: DPP for xor 1/2 (VALU pipe), ds_swizzle
// immediates for 4/8/16 (no addr calc), bpermute only for 32.
// ---------------------------------------------------------------------------
template <int M>
__device__ __forceinline__ float shfx(float x) {
  if constexpr (M == 1)
    return __int_as_float(__builtin_amdgcn_mov_dpp(__float_as_int(x), 0xB1, 0xF, 0xF, true));
  else if constexpr (M == 2)
    return __int_as_float(__builtin_amdgcn_mov_dpp(__float_as_int(x), 0x4E, 0xF, 0xF, true));
  else if constexpr (M == 4)
    return __int_as_float(__builtin_amdgcn_ds_swizzle(__float_as_int(x), 0x101F));
  else if constexpr (M == 8)
    return __int_as_float(__builtin_amdgcn_ds_swizzle(__float_as_int(x), 0x201F));
  else if constexpr (M == 16)
    return __int_as_float(__builtin_amdgcn_ds_swizzle(__float_as_int(x), 0x401F));
  else
    return __shfl_xor(x, 32, 64);
}

// Quadratic spline activation: interval-find via float exponent + 1 load + 2 fma.
__device__ __forceinline__ float qspline(float x, const float4* __restrict__ qL, int w) {
  x = fminf(fmaxf(x, -8.0f), 7.9999990f);
  float ax = fabsf(x);
  unsigned bits = __float_as_uint(ax);
  int e = (int)(bits >> 23) - 127;
  int ce = e + ((bits & 0x7fffffu) ? 1 : 0);
  int m = (x > 0.f) ? (17 + e) : (5 - ce);
  m = (ax < 0.03125f) ? ((x < 0.f) ? 10 : 11) : m;
  float4 qc = qL[(m - 2) * HALF + w];
  float u = x - qc.w;
  return fmaf(u, fmaf(u, qc.z, qc.y), qc.x);
}

// Cooperative stage of 5 steps' tables (5*1024 float2 = 40 KB) into LDS.
// 2560 float4 / 512 threads = 5 independent dwordx4 per thread, coalesced.
#define STAGE(off5) do {                                                      \
    const float4* _src = (const float4*)(csL + (off5) * 1024);                \
    float4* _dst = (float4*)csS;                                              \
    _Pragma("unroll") for (int k = 0; k < 5; ++k)                             \
      _dst[tid + k * 512] = _src[tid + k * 512];                              \
  } while (0)

// butterfly step dd<4 from LDS slot sl: partner = reg ^ (8>>dd), same lane
#define CSTEPL(sl, dd) do {                                                   \
    const int _mr = 8 >> (dd);                                                \
    _Pragma("unroll") for (int r = 0; r < 16; ++r)                            \
      if ((r & _mr) == 0) {                                                   \
        float2 v = csS[(sl) * 1024 + r * 64 + lane];                          \
        float a0 = s0[r], b0 = s0[r + _mr];                                   \
        s0[r]       = fmaf(a0, v.x, b0 * v.y);                                \
        s0[r + _mr] = fmaf(b0, v.x, -(a0 * v.y));                             \
      }                                                                       \
  } while (0)

// butterfly step dd>=4 from LDS slot sl: partner = lane ^ MM, same reg
#define LSTEPL(sl, MM) do {                                                   \
    _Pragma("unroll") for (int r = 0; r < 16; ++r) {                          \
      float2 v = csS[(sl) * 1024 + r * 64 + lane];                            \
      float p0 = shfx<MM>(s0[r]);                                             \
      s0[r] = fmaf(s0[r], v.x, p0 * v.y);                                     \
    }                                                                         \
  } while (0)

// ---------------------------------------------------------------------------
// Main kernel: 512-thread blocks (8 waves), ONE row per wave. The cs table is
// staged into LDS once per block in 5-step 40 KB chunks -- same total staging
// traffic as R7 (512 blocks) but 4096 waves = 4 waves/SIMD (double the
// latency hiding) and half the per-wave serial work. Steps 0-3 intra-lane reg
// pairs; steps 4-9 lane shuffles. Layer loop rolled (fits I$).
// ---------------------------------------------------------------------------
__global__ __launch_bounds__(512, 4) void fwd_kernel(
    const float* __restrict__ X, const float2* __restrict__ cs,
    const float4* __restrict__ qt, float* __restrict__ out) {
  __shared__ float2 csS[5 * 1024];   // 40 KB
  int tid = threadIdx.x;
  int lane = tid & 63;
  int wv = tid >> 6;                       // 0..7
  int row = blockIdx.x * 8 + wv;

  const float* xp = X + (long)row * NIN;
  float s0[16];
#pragma unroll
  for (int r = 0; r < 16; ++r) {
    int w = r * 64 + lane;
    s0[r] = (w < NIN) ? xp[w] : 0.f;
  }

#pragma unroll 1
  for (int i = 0; i < DEPTH; ++i) {
    const float2* csL = cs + i * (BDEPTH * 1024);

    __syncthreads();               // prior half consumed
    STAGE(0);                      // steps 0..4
    __syncthreads();
    CSTEPL(0, 0);
    CSTEPL(1, 1);
    CSTEPL(2, 2);
    CSTEPL(3, 3);
    LSTEPL(4, 32);

    __syncthreads();               // half consumed
    STAGE(5);                      // steps 5..9
    __syncthreads();
    LSTEPL(0, 16);
    LSTEPL(1, 8);
    LSTEPL(2, 4);
    LSTEPL(3, 2);
    LSTEPL(4, 1);

    if (i != DEPTH - 1) {
      const float4* qL = qt + i * (NQ * HALF);
#pragma unroll
      for (int r = 8; r < 16; ++r) {
        int w = ((r - 8) << 6) | lane;
        s0[r - 8] += qspline(s0[r], qL, w);
      }
    }
  }

  float* op = out + (long)row * NIN;
#pragma unroll
  for (int r = 0; r < 13; ++r) {
    int w = r * 64 + lane;
    if (w < NIN) op[w] = s0[r];
  }
}

extern "C" void kernel_launch(void* const* d_in, const int* in_sizes, int n_in,
                              void* d_out, int out_size, void* d_ws, size_t ws_size,
                              hipStream_t stream) {
  const float* X  = (const float*)d_in[0];
  const float* bp = (const float*)d_in[1];   // [8,512,10]
  const float* sc = (const float*)d_in[2];   // [7,512,20]
  float* out = (float*)d_out;

  float2* cs = (float2*)d_ws;                                   // 655,360 B
  float4* qt = (float4*)((char*)d_ws + DEPTH * BDEPTH * 1024 * sizeof(float2)); // 1,032,192 B

  int prep_threads = DEPTH * BDEPTH * 1024 + (DEPTH - 1) * NQ * HALF; // 146,432
  prep_kernel<<<(prep_threads + 255) / 256, 256, 0, stream>>>(bp, sc, cs, qt);
  fwd_kernel<<<BATCH / 8, 512, 0, stream>>>(X, cs, qt, out);
}